// Round 11
// baseline (171.879 us; speedup 1.0000x reference)
//
#include <hip/hip_runtime.h>
#include <stdint.h>

typedef unsigned short ushort_t;
typedef __attribute__((ext_vector_type(8))) short short8;
typedef __attribute__((ext_vector_type(4))) float floatx4;
typedef __attribute__((ext_vector_type(16))) float floatx16;
typedef __attribute__((ext_vector_type(4))) unsigned short ushortx4;
typedef __attribute__((ext_vector_type(8))) unsigned short ushortx8;

#define B_   16
#define CIN  128
#define CH   256
#define HW   96
#define HP   98

// ws layout (bytes)
#define XPAD_ELEMS (B_*HP*HP*CIN)            // bf16 elems
#define HPAD_ELEMS (B_*HP*HP*CH)             // bf16 elems
#define XPAD_OFF 0
#define HPAD_OFF (XPAD_ELEMS*2)
#define W1T_OFF  (HPAD_OFF + HPAD_ELEMS*2)
#define W2T_OFF  (W1T_OFF + 256*1152*2)

__device__ __forceinline__ ushort_t f2bf(float f){
  uint32_t u = __float_as_uint(f);
  u += 0x7FFF + ((u >> 16) & 1);   // RNE
  return (ushort_t)(u >> 16);
}
__device__ __forceinline__ float bf2f(ushort_t h){
  return __uint_as_float(((uint32_t)h) << 16);
}
__device__ __forceinline__ void async_ld16(void* lds, const void* g){
  __builtin_amdgcn_global_load_lds(
      (const __attribute__((address_space(1))) void*)g,
      (__attribute__((address_space(3))) void*)lds, 16, 0, 0);
}

// Zero one border word of a padded NHWC tensor. C2 = channels/2 (u32 words/cell).
__device__ __forceinline__ void zb(uint32_t* base, int C2, int tid){
  int perimg = 388*C2;
  int b = tid / perimg; int r = tid % perimg;
  int cell = r / C2;    int cu = r % C2;
  int y, x;
  if      (cell < 98)  { y = 0;            x = cell;       }
  else if (cell < 196) { y = 97;           x = cell - 98;  }
  else if (cell < 292) { y = cell - 195;   x = 0;          }
  else                 { y = cell - 291;   x = 97;         }
  base[((b*HP + y)*HP + x)*C2 + cu] = 0u;
}

// Fused prep: blocks [0,4608) = transform_x (NCHW fp32 -> padded NHWC bf16,
// full 256B-line stores); blocks [4608,10434) = border zeroing + w transforms.
__global__ __launch_bounds__(256) void prep_all(const float* __restrict__ x,
                                                const float* __restrict__ w1,
                                                const float* __restrict__ w2,
                                                uint32_t* __restrict__ xpadw,
                                                uint32_t* __restrict__ hpadw,
                                                ushort_t* __restrict__ w1t,
                                                float* __restrict__ w2t,
                                                ushort_t* __restrict__ xpad){
  __shared__ float lds[128][33];
  int bidx = blockIdx.x;
  int t = threadIdx.x;
  if (bidx < 4608){
    int xt = bidx % 3; int y = (bidx/3) % 96; int b = bidx/288;
    int x0 = xt*32;
    #pragma unroll
    for (int rep=0; rep<16; ++rep){
      int idx = rep*256 + t;
      int ci = idx >> 5, xj = idx & 31;
      lds[ci][xj] = x[((b*CIN + ci)*HW + y)*HW + x0 + xj];
    }
    __syncthreads();
    int px = t & 31, oc = t >> 5;      // oc = 16-channel group (0..7)
    ushort_t* dst = &xpad[((b*HP + y+1)*HP + x0+px+1)*CIN + oc*16];
    ushortx8 v0, v1;
    #pragma unroll
    for (int k=0;k<8;k++) v0[k] = f2bf(lds[oc*16+k][px]);
    #pragma unroll
    for (int k=0;k<8;k++) v1[k] = f2bf(lds[oc*16+8+k][px]);
    *(ushortx8*)dst = v0;
    *(ushortx8*)(dst+8) = v1;
  } else {
    int tid = (bidx - 4608)*256 + t;
    const int NZX = B_*388*64;
    const int NZH = B_*388*128;
    const int NW1 = 256*1152;
    if (tid < NZX){
      zb(xpadw, 64, tid);
    } else if (tid < NZX + NZH){
      zb(hpadw, 128, tid - NZX);
    } else if (tid < NZX + NZH + NW1){
      int r = tid - (NZX + NZH);
      int o = r / 1152, k = r - o*1152;
      int tap = k >> 7, c = k & 127;
      w1t[r] = f2bf(w1[(o*CIN + c)*9 + tap]);
    } else {
      int r = tid - (NZX + NZH + NW1);   // < 4608
      int ch = r & 1, c = (r >> 1) & 255, tap = r >> 9;
      w2t[r] = w2[(ch*CH + c)*9 + tap];
    }
  }
}

// ---------------------------------------------------------------------------
// conv1 v8: v6's exact structure (BM=256, BN=192, BK=64, 18 K-tiles, 4Mx2N
// waves 64x96, A 2-buf / B 3-buf, T2 both-sides swizzle, vmcnt(3) per-tile
// ledger, 4 phases / 8 barriers per tile, T5 setprio, 1-phase frag prefetch).
// ONLY change: MFMA shape 16x16x32 -> 32x32x16 (m119: 2495 vs 2176 TF).
// Wave tile = 2x3 frags of 32x32; K-tile = 4 ksteps of K=16; per-kstep
// phases of 6 MFMAs. Frag read: lane reads row (lane&31), k-oct
// kstep*2+(lane>>5), same XOR swizzle -> still conflict-free.
// C/D layout (m74/m101): col=lane&31, row=(reg&3)+8*(reg>>2)+4*(lane>>5);
// reg-quad g covers 4 consecutive out-channels -> ushortx4 stores.
// ---------------------------------------------------------------------------
#define C1_TILE(KT, VMN, SA, SB) { \
  asm volatile("s_waitcnt vmcnt(" #VMN ")" ::: "memory"); \
  __builtin_amdgcn_s_barrier(); \
  __builtin_amdgcn_sched_barrier(0); \
  const int kt_ = (KT); \
  const ushort_t* Ab = &Alds[(kt_ & 1) * 16384]; \
  const ushort_t* Bb = &Blds[(kt_ % 3) * 12288]; \
  short8 aS0[2], aS1[2], aS2[2], aS3[2]; \
  short8 bS0[3], bS1[3], bS2[3], bS3[3]; \
  /* R0: kstep0 frags (exposed at tile entry) */ \
  _Pragma("unroll") \
  for (int nf=0; nf<3; ++nf) bS0[nf] = *(const short8*)&Bb[bbase_r + nf*2048 + ko0]; \
  _Pragma("unroll") \
  for (int mf=0; mf<2; ++mf) aS0[mf] = *(const short8*)&Ab[abase_r + mf*2048 + ko0]; \
  /* ---- P0: read kstep1 frags; stage A(kt+1) j0,j1; MFMA kstep0 ---- */ \
  _Pragma("unroll") \
  for (int nf=0; nf<3; ++nf) bS1[nf] = *(const short8*)&Bb[bbase_r + nf*2048 + ko1]; \
  _Pragma("unroll") \
  for (int mf=0; mf<2; ++mf) aS1[mf] = *(const short8*)&Ab[abase_r + mf*2048 + ko1]; \
  if (SA) { \
    const int ka_ = kt_ + 1; const int ab_ = (ka_ & 1) * 16384; \
    async_ld16(&Alds[ab_ +     0 + adst], &w1t[asrc +       0 + ka_*64]); \
    async_ld16(&Alds[ab_ +  4096 + adst], &w1t[asrc +   73728 + ka_*64]); \
  } \
  __builtin_amdgcn_s_barrier(); \
  __builtin_amdgcn_sched_barrier(0); \
  __builtin_amdgcn_s_setprio(1); \
  _Pragma("unroll") \
  for (int mf=0; mf<2; ++mf) \
    _Pragma("unroll") \
    for (int nf=0; nf<3; ++nf) \
      acc[mf][nf] = __builtin_amdgcn_mfma_f32_32x32x16_bf16(aS0[mf], bS0[nf], acc[mf][nf], 0,0,0); \
  __builtin_amdgcn_s_setprio(0); \
  __builtin_amdgcn_s_barrier(); \
  __builtin_amdgcn_sched_barrier(0); \
  /* ---- P1: read kstep2 frags; stage A(kt+1) j2,j3; MFMA kstep1 ---- */ \
  _Pragma("unroll") \
  for (int nf=0; nf<3; ++nf) bS2[nf] = *(const short8*)&Bb[bbase_r + nf*2048 + ko2]; \
  _Pragma("unroll") \
  for (int mf=0; mf<2; ++mf) aS2[mf] = *(const short8*)&Ab[abase_r + mf*2048 + ko2]; \
  if (SA) { \
    const int ka_ = kt_ + 1; const int ab_ = (ka_ & 1) * 16384; \
    async_ld16(&Alds[ab_ +  8192 + adst], &w1t[asrc + 2*73728 + ka_*64]); \
    async_ld16(&Alds[ab_ + 12288 + adst], &w1t[asrc + 3*73728 + ka_*64]); \
  } \
  __builtin_amdgcn_s_barrier(); \
  __builtin_amdgcn_sched_barrier(0); \
  __builtin_amdgcn_s_setprio(1); \
  _Pragma("unroll") \
  for (int mf=0; mf<2; ++mf) \
    _Pragma("unroll") \
    for (int nf=0; nf<3; ++nf) \
      acc[mf][nf] = __builtin_amdgcn_mfma_f32_32x32x16_bf16(aS1[mf], bS1[nf], acc[mf][nf], 0,0,0); \
  __builtin_amdgcn_s_setprio(0); \
  __builtin_amdgcn_s_barrier(); \
  __builtin_amdgcn_sched_barrier(0); \
  /* ---- P2: read kstep3 frags; stage B(kt+2) j0,j1; MFMA kstep2 ---- */ \
  _Pragma("unroll") \
  for (int nf=0; nf<3; ++nf) bS3[nf] = *(const short8*)&Bb[bbase_r + nf*2048 + ko3]; \
  _Pragma("unroll") \
  for (int mf=0; mf<2; ++mf) aS3[mf] = *(const short8*)&Ab[abase_r + mf*2048 + ko3]; \
  if (SB) { \
    const int kb_ = kt_ + 2; \
    const int tapb_ = kb_ >> 1; \
    const int dyb_ = tapb_/3; const int dxb_ = tapb_ - dyb_*3; \
    const int bdb_ = (dyb_*HP + dxb_)*CIN + (kb_&1)*64; \
    const int bb_ = (kb_ % 3) * 12288; \
    async_ld16(&Blds[bb_ +    0 + bdst], &xpad[bsrc +            bdb_]); \
    async_ld16(&Blds[bb_ + 4096 + bdst], &xpad[bsrc + 2*HP*CIN + bdb_]); \
  } \
  __builtin_amdgcn_s_barrier(); \
  __builtin_amdgcn_sched_barrier(0); \
  __builtin_amdgcn_s_setprio(1); \
  _Pragma("unroll") \
  for (int mf=0; mf<2; ++mf) \
    _Pragma("unroll") \
    for (int nf=0; nf<3; ++nf) \
      acc[mf][nf] = __builtin_amdgcn_mfma_f32_32x32x16_bf16(aS2[mf], bS2[nf], acc[mf][nf], 0,0,0); \
  __builtin_amdgcn_s_setprio(0); \
  __builtin_amdgcn_s_barrier(); \
  __builtin_amdgcn_sched_barrier(0); \
  /* ---- P3: stage B(kt+2) j2; MFMA kstep3 ---- */ \
  if (SB) { \
    const int kb_ = kt_ + 2; \
    const int tapb_ = kb_ >> 1; \
    const int dyb_ = tapb_/3; const int dxb_ = tapb_ - dyb_*3; \
    const int bdb_ = (dyb_*HP + dxb_)*CIN + (kb_&1)*64; \
    const int bb_ = (kb_ % 3) * 12288; \
    async_ld16(&Blds[bb_ + 8192 + bdst], &xpad[bsrc + 4*HP*CIN + bdb_]); \
  } \
  __builtin_amdgcn_s_barrier(); \
  __builtin_amdgcn_sched_barrier(0); \
  __builtin_amdgcn_s_setprio(1); \
  _Pragma("unroll") \
  for (int mf=0; mf<2; ++mf) \
    _Pragma("unroll") \
    for (int nf=0; nf<3; ++nf) \
      acc[mf][nf] = __builtin_amdgcn_mfma_f32_32x32x16_bf16(aS3[mf], bS3[nf], acc[mf][nf], 0,0,0); \
  __builtin_amdgcn_s_setprio(0); \
}

__global__ __launch_bounds__(512, 1) void conv1(const ushort_t* __restrict__ xpad,
                                                const ushort_t* __restrict__ w1t,
                                                const float* __restrict__ b1,
                                                ushort_t* __restrict__ hpad){
  __shared__ __align__(16) ushort_t Alds[2*16384];   // 2 bufs x 256 rows x 64 (64 KB)
  __shared__ __align__(16) ushort_t Blds[3*12288];   // 3 bufs x 192 rows x 64 (72 KB)
  int orig = blockIdx.x;
  int bid = (orig & 7) * 96 + (orig >> 3);           // XCD swizzle, 768 % 8 == 0
  int b = bid / 48; int rem = bid - b*48;
  int y0 = (rem/3)*6, x0 = (rem - (rem/3)*3)*32;     // 6y x 32x pixel tile
  int t = threadIdx.x;
  int lane = t & 63, wave = t >> 6;
  int wm = wave & 3, wn = wave >> 2;                 // 4M x 2N waves (wave tile 64x96)

  // staging maps (granule v = j*512 + t; row = v>>3; stored oct = v&7 holds
  // logical oct (v&7)^(row&7) -> source pre-swizzled, LDS dest linear)
  const int arow0 = t >> 3;                          // 0..63 (j adds 64 each)
  const int soct  = (t & 7) ^ (arow0 & 7);           // same for all j (64%8==0)
  const int adst  = t * 8;                           // + j*4096 + buf*16384
  const int asrc  = arow0 * 1152 + soct * 8;         // + j*73728 + kt*64
  const int bty0  = arow0 >> 5, btx0 = arow0 & 31;   // B row = pixel index
  const int bdst  = t * 8;                           // + j*4096 + buf*12288
  const int bsrc  = ((b*HP + y0 + bty0)*HP + x0 + btx0)*CIN + soct * 8; // + j*2*HP*CIN + bd

  // 32x32x16 fragment addressing: lane holds row (lane&31), k-oct kstep*2+(lane>>5)
  const int r32 = lane & 31, hi = lane >> 5;
  const int ko0 = ((0 + hi) ^ (r32 & 7)) * 8;
  const int ko1 = ((2 + hi) ^ (r32 & 7)) * 8;
  const int ko2 = ((4 + hi) ^ (r32 & 7)) * 8;
  const int ko3 = ((6 + hi) ^ (r32 & 7)) * 8;
  const int abase_r = (wm*64 + r32) * 64;            // + mf*2048 (mf 0..1)
  const int bbase_r = (wn*96 + r32) * 64;            // + nf*2048 (nf 0..2)

  floatx16 acc[2][3];
  #pragma unroll
  for (int i=0;i<2;i++)
    #pragma unroll
    for (int j=0;j<3;j++)
      #pragma unroll
      for (int e=0;e<16;e++) acc[i][j][e] = 0.f;

  // prologue: ledger order B-for-0(3), A-for-0(4), B-for-1(3)
  #pragma unroll
  for (int j=0;j<3;++j) async_ld16(&Blds[0     + j*4096 + bdst], &xpad[bsrc + j*(2*HP*CIN)]);
  #pragma unroll
  for (int j=0;j<4;++j) async_ld16(&Alds[0     + j*4096 + adst], &w1t[asrc + j*73728]);
  #pragma unroll
  for (int j=0;j<3;++j) async_ld16(&Blds[12288 + j*4096 + bdst], &xpad[bsrc + j*(2*HP*CIN) + 64]);

  for (int kt=0; kt<16; ++kt){
    C1_TILE(kt, 3, 1, 1)
  }
  C1_TILE(16, 3, 1, 0)
  C1_TILE(17, 0, 0, 0)

  // epilogue: +bias, ReLU, bf16, store padded NHWC h.
  // C/D: col=lane&31 (pixel), row=(reg&3)+8*(reg>>2)+4*hi (out-ch within frag).
  #pragma unroll
  for (int mf=0; mf<2; ++mf){
    #pragma unroll
    for (int g=0; g<4; ++g){
      int o = wm*64 + mf*32 + g*8 + hi*4;
      float bias0 = b1[o], bias1 = b1[o+1], bias2 = b1[o+2], bias3 = b1[o+3];
      #pragma unroll
      for (int nf=0; nf<3; ++nf){
        int n = wn*96 + nf*32 + r32;
        int ty = n >> 5, tx = n & 31;
        ushortx4 v;
        v[0] = f2bf(fmaxf(acc[mf][nf][g*4+0] + bias0, 0.f));
        v[1] = f2bf(fmaxf(acc[mf][nf][g*4+1] + bias1, 0.f));
        v[2] = f2bf(fmaxf(acc[mf][nf][g*4+2] + bias2, 0.f));
        v[3] = f2bf(fmaxf(acc[mf][nf][g*4+3] + bias3, 0.f));
        *(ushortx4*)&hpad[((b*HP + y0+ty+1)*HP + (x0+tx+1))*CH + o] = v;
      }
    }
  }
}

// conv2: LDS-staged direct 3x3. Block = 8x8 output tile, halo 10x10 cells x 512B
// staged into LDS (51.2 KB) via global_load_lds: LDS dest linear, global SOURCE
// pre-swizzled chunk ^ (cell&7); reads apply the same XOR (both-sides involution).
// Wave = channel quarter (w addresses wave-uniform -> scalar cache); lane = pixel.
__global__ __launch_bounds__(256) void conv2(const ushort_t* __restrict__ hpad,
                                             const float* __restrict__ w2t,
                                             const float* __restrict__ b2,
                                             float* __restrict__ out){
  __shared__ __align__(16) ushort_t hlds[25600];   // 100 cells * 256 ushorts
  __shared__ float part[4][64][2];
  int bid = blockIdx.x;              // 2304 = 16 b * 12 yt * 12 xt
  int b = bid / 144; int rem = bid - b*144;
  int yt = rem / 12, xt = rem - yt*12;
  int y0 = yt*8, x0 = xt*8;          // padded window base = (y0, x0)
  int t = threadIdx.x;
  int wave = t >> 6, lane = t & 63;

  // stage 3200 x 16B chunks, pre-swizzled source
  for (int pass=0; pass<13; ++pass){
    int u = pass*256 + t;
    if (u < 3200){
      int cell = u >> 5, cf = u & 31;
      int hy = cell / 10, hx = cell - hy*10;
      const ushort_t* src = hpad + ((b*HP + y0+hy)*HP + (x0+hx))*CH
                                 + ((cf ^ (cell & 7)) << 3);
      async_ld16(&hlds[(pass*256 + wave*64)*8], src);
    }
  }
  __syncthreads();

  int q = __builtin_amdgcn_readfirstlane(wave);    // channel quarter, provably uniform
  int ty = lane >> 3, tx = lane & 7;
  float a0 = 0.f, a1 = 0.f;
  for (int tap=0; tap<9; ++tap){
    int dy = tap/3, dxx = tap - dy*3;
    int cell = (ty+dy)*10 + (tx+dxx);
    int s = cell & 7;
    const float* wp = w2t + (tap*256 + q*64)*2;    // scalar pointer
    #pragma unroll
    for (int g=0; g<8; ++g){
      int j = q*8 + g;
      ushortx8 hv = *(const ushortx8*)&hlds[cell*256 + ((j ^ s) << 3)];
      #pragma unroll
      for (int i=0;i<8;i++){
        float hf = bf2f(hv[i]);
        a0 = fmaf(hf, wp[(g*8+i)*2    ], a0);
        a1 = fmaf(hf, wp[(g*8+i)*2 + 1], a1);
      }
    }
  }
  part[wave][lane][0] = a0;
  part[wave][lane][1] = a1;
  __syncthreads();
  if (t < 128){
    int sel = t >> 6, pix = t & 63;
    float v = part[0][pix][sel] + part[1][pix][sel]
            + part[2][pix][sel] + part[3][pix][sel] + b2[sel];
    int yy = y0 + (pix >> 3), xx = x0 + (pix & 7);
    out[(b*2 + sel)*9216 + yy*96 + xx] = v;
  }
}

extern "C" void kernel_launch(void* const* d_in, const int* in_sizes, int n_in,
                              void* d_out, int out_size, void* d_ws, size_t ws_size,
                              hipStream_t stream){
  const float* x  = (const float*)d_in[0];
  const float* w1 = (const float*)d_in[1];
  const float* b1 = (const float*)d_in[2];
  const float* w2 = (const float*)d_in[3];
  const float* b2 = (const float*)d_in[4];
  float* out = (float*)d_out;
  char* ws = (char*)d_ws;
  ushort_t* xpad = (ushort_t*)(ws + XPAD_OFF);
  ushort_t* hpad = (ushort_t*)(ws + HPAD_OFF);
  ushort_t* w1t  = (ushort_t*)(ws + W1T_OFF);
  float*    w2t  = (float*)(ws + W2T_OFF);

  hipLaunchKernelGGL(prep_all, dim3(10434), dim3(256), 0, stream,
                     x, w1, w2, (uint32_t*)xpad, (uint32_t*)hpad, w1t, w2t, xpad);
  hipLaunchKernelGGL(conv1, dim3(768),  dim3(512), 0, stream, xpad, w1t, b1, hpad);
  hipLaunchKernelGGL(conv2, dim3(2304), dim3(256), 0, stream, hpad, w2t, b2, out);
}

// Round 12
// 164.041 us; speedup vs baseline: 1.0478x; 1.0478x over previous
//
#include <hip/hip_runtime.h>
#include <stdint.h>

typedef unsigned short ushort_t;
typedef __attribute__((ext_vector_type(8))) short short8;
typedef __attribute__((ext_vector_type(4))) float floatx4;
typedef __attribute__((ext_vector_type(4))) unsigned short ushortx4;
typedef __attribute__((ext_vector_type(8))) unsigned short ushortx8;

#define B_   16
#define CIN  128
#define CH   256
#define HW   96
#define HP   98

// ws layout (bytes)
#define XPAD_ELEMS (B_*HP*HP*CIN)            // bf16 elems
#define HPAD_ELEMS (B_*HP*HP*CH)             // bf16 elems
#define XPAD_OFF 0
#define HPAD_OFF (XPAD_ELEMS*2)
#define W1T_OFF  (HPAD_OFF + HPAD_ELEMS*2)
#define W2T_OFF  (W1T_OFF + 256*1152*2)

__device__ __forceinline__ ushort_t f2bf(float f){
  uint32_t u = __float_as_uint(f);
  u += 0x7FFF + ((u >> 16) & 1);   // RNE
  return (ushort_t)(u >> 16);
}
__device__ __forceinline__ float bf2f(ushort_t h){
  return __uint_as_float(((uint32_t)h) << 16);
}
__device__ __forceinline__ void async_ld16(void* lds, const void* g){
  __builtin_amdgcn_global_load_lds(
      (const __attribute__((address_space(1))) void*)g,
      (__attribute__((address_space(3))) void*)lds, 16, 0, 0);
}

// Zero one border word of a padded NHWC tensor. C2 = channels/2 (u32 words/cell).
__device__ __forceinline__ void zb(uint32_t* base, int C2, int tid){
  int perimg = 388*C2;
  int b = tid / perimg; int r = tid % perimg;
  int cell = r / C2;    int cu = r % C2;
  int y, x;
  if      (cell < 98)  { y = 0;            x = cell;       }
  else if (cell < 196) { y = 97;           x = cell - 98;  }
  else if (cell < 292) { y = cell - 195;   x = 0;          }
  else                 { y = cell - 291;   x = 97;         }
  base[((b*HP + y)*HP + x)*C2 + cu] = 0u;
}

// Fused prep: blocks [0,4608) = transform_x (NCHW fp32 -> padded NHWC bf16,
// full 256B-line stores); blocks [4608,10434) = border zeroing + w transforms.
__global__ __launch_bounds__(256) void prep_all(const float* __restrict__ x,
                                                const float* __restrict__ w1,
                                                const float* __restrict__ w2,
                                                uint32_t* __restrict__ xpadw,
                                                uint32_t* __restrict__ hpadw,
                                                ushort_t* __restrict__ w1t,
                                                float* __restrict__ w2t,
                                                ushort_t* __restrict__ xpad){
  __shared__ float lds[128][33];
  int bidx = blockIdx.x;
  int t = threadIdx.x;
  if (bidx < 4608){
    int xt = bidx % 3; int y = (bidx/3) % 96; int b = bidx/288;
    int x0 = xt*32;
    #pragma unroll
    for (int rep=0; rep<16; ++rep){
      int idx = rep*256 + t;
      int ci = idx >> 5, xj = idx & 31;
      lds[ci][xj] = x[((b*CIN + ci)*HW + y)*HW + x0 + xj];
    }
    __syncthreads();
    int px = t & 31, oc = t >> 5;      // oc = 16-channel group (0..7)
    ushort_t* dst = &xpad[((b*HP + y+1)*HP + x0+px+1)*CIN + oc*16];
    ushortx8 v0, v1;
    #pragma unroll
    for (int k=0;k<8;k++) v0[k] = f2bf(lds[oc*16+k][px]);
    #pragma unroll
    for (int k=0;k<8;k++) v1[k] = f2bf(lds[oc*16+8+k][px]);
    *(ushortx8*)dst = v0;
    *(ushortx8*)(dst+8) = v1;
  } else {
    int tid = (bidx - 4608)*256 + t;
    const int NZX = B_*388*64;
    const int NZH = B_*388*128;
    const int NW1 = 256*1152;
    if (tid < NZX){
      zb(xpadw, 64, tid);
    } else if (tid < NZX + NZH){
      zb(hpadw, 128, tid - NZX);
    } else if (tid < NZX + NZH + NW1){
      int r = tid - (NZX + NZH);
      int o = r / 1152, k = r - o*1152;
      int tap = k >> 7, c = k & 127;
      w1t[r] = f2bf(w1[(o*CIN + c)*9 + tap]);
    } else {
      int r = tid - (NZX + NZH + NW1);   // < 4608
      int ch = r & 1, c = (r >> 1) & 255, tap = r >> 9;
      w2t[r] = w2[(ch*CH + c)*9 + tap];
    }
  }
}

// ---------------------------------------------------------------------------
// conv1 v9: the proven v5 4-phase schedule re-cut for 2 blocks/CU.
// BM=128, BN=128 (4y x 32x), BK=64, 18 K-tiles. 256 thr / 4 waves (2M x 2N,
// wave tile 64x64, acc[4][4] of 16x16x32). LDS = A 2-buf (32KB) + B 3-buf
// (48KB) = 80KB -> 2 blocks/CU: one block's MFMAs fill the other block's
// barrier/waitcnt stalls (the m114 mechanism the 1-block/CU configs lacked).
// T2 both-sides swizzle unchanged. Ledger: tile kt stages A(kt+1) x4 then
// B(kt+2) x4; entry vmcnt(4) leaves only B(kt+1) in flight. kt=17 peeled
// with vmcnt(0). Per-element accumulation order unchanged (kt asc, k0 then
// k1, same MFMA shape) -> output bit-identical (absmax must stay 0.015625).
// ---------------------------------------------------------------------------
#define C1_TILE(KT, VMN, SA, SB) { \
  asm volatile("s_waitcnt vmcnt(" #VMN ")" ::: "memory"); \
  __builtin_amdgcn_s_barrier(); \
  __builtin_amdgcn_sched_barrier(0); \
  const int kt_ = (KT); \
  const ushort_t* Ab = &Alds[(kt_ & 1) * 8192]; \
  const ushort_t* Bb = &Blds[(kt_ % 3) * 8192]; \
  short8 a0[4], a1[4], b0[2], b1[2], b2v[2], b3[2]; \
  /* ---- P0: read a0,b0 (k0, nf0-1); stage A(kt+1) j0,j1; MFMA a0xb0 ---- */ \
  _Pragma("unroll") \
  for (int nf=0; nf<2; ++nf) b0[nf] = *(const short8*)&Bb[bbase_r + nf*1024 + koff0]; \
  _Pragma("unroll") \
  for (int mf=0; mf<4; ++mf) a0[mf] = *(const short8*)&Ab[abase_r + mf*1024 + koff0]; \
  if (SA) { \
    const int ka_ = kt_ + 1; const int ab_ = (ka_ & 1) * 8192; \
    async_ld16(&Alds[ab_ +    0 + adst], &w1t[asrc +       0 + ka_*64]); \
    async_ld16(&Alds[ab_ + 2048 + adst], &w1t[asrc +   36864 + ka_*64]); \
  } \
  __builtin_amdgcn_s_barrier(); \
  asm volatile("s_waitcnt lgkmcnt(0)" ::: "memory"); \
  __builtin_amdgcn_sched_barrier(0); \
  __builtin_amdgcn_s_setprio(1); \
  _Pragma("unroll") \
  for (int mf=0; mf<4; ++mf) \
    _Pragma("unroll") \
    for (int nf=0; nf<2; ++nf) \
      acc[mf][nf] = __builtin_amdgcn_mfma_f32_16x16x32_bf16(a0[mf], b0[nf], acc[mf][nf], 0,0,0); \
  __builtin_amdgcn_s_setprio(0); \
  __builtin_amdgcn_s_barrier(); \
  __builtin_amdgcn_sched_barrier(0); \
  /* ---- P1: read b1 (k0, nf2-3); stage A(kt+1) j2,j3; MFMA a0xb1 ---- */ \
  _Pragma("unroll") \
  for (int nf=0; nf<2; ++nf) b1[nf] = *(const short8*)&Bb[bbase_r + (nf+2)*1024 + koff0]; \
  if (SA) { \
    const int ka_ = kt_ + 1; const int ab_ = (ka_ & 1) * 8192; \
    async_ld16(&Alds[ab_ + 4096 + adst], &w1t[asrc + 2*36864 + ka_*64]); \
    async_ld16(&Alds[ab_ + 6144 + adst], &w1t[asrc + 3*36864 + ka_*64]); \
  } \
  __builtin_amdgcn_s_barrier(); \
  asm volatile("s_waitcnt lgkmcnt(0)" ::: "memory"); \
  __builtin_amdgcn_sched_barrier(0); \
  __builtin_amdgcn_s_setprio(1); \
  _Pragma("unroll") \
  for (int mf=0; mf<4; ++mf) \
    _Pragma("unroll") \
    for (int nf=0; nf<2; ++nf) \
      acc[mf][nf+2] = __builtin_amdgcn_mfma_f32_16x16x32_bf16(a0[mf], b1[nf], acc[mf][nf+2], 0,0,0); \
  __builtin_amdgcn_s_setprio(0); \
  __builtin_amdgcn_s_barrier(); \
  __builtin_amdgcn_sched_barrier(0); \
  /* ---- P2: read a1,b2 (k1, nf0-1); stage B(kt+2) j0,j1; MFMA a1xb2 ---- */ \
  _Pragma("unroll") \
  for (int nf=0; nf<2; ++nf) b2v[nf] = *(const short8*)&Bb[bbase_r + nf*1024 + koff1]; \
  _Pragma("unroll") \
  for (int mf=0; mf<4; ++mf) a1[mf] = *(const short8*)&Ab[abase_r + mf*1024 + koff1]; \
  if (SB) { \
    const int kb_ = kt_ + 2; \
    const int tapb_ = kb_ >> 1; \
    const int dyb_ = tapb_/3; const int dxb_ = tapb_ - dyb_*3; \
    const int bdb_ = (dyb_*HP + dxb_)*CIN + (kb_&1)*64; \
    const int bb_ = (kb_ % 3) * 8192; \
    async_ld16(&Blds[bb_ +    0 + bdst], &xpad[bsrc +            bdb_]); \
    async_ld16(&Blds[bb_ + 2048 + bdst], &xpad[bsrc +   HP*CIN + bdb_]); \
  } \
  __builtin_amdgcn_s_barrier(); \
  asm volatile("s_waitcnt lgkmcnt(0)" ::: "memory"); \
  __builtin_amdgcn_sched_barrier(0); \
  __builtin_amdgcn_s_setprio(1); \
  _Pragma("unroll") \
  for (int mf=0; mf<4; ++mf) \
    _Pragma("unroll") \
    for (int nf=0; nf<2; ++nf) \
      acc[mf][nf] = __builtin_amdgcn_mfma_f32_16x16x32_bf16(a1[mf], b2v[nf], acc[mf][nf], 0,0,0); \
  __builtin_amdgcn_s_setprio(0); \
  __builtin_amdgcn_s_barrier(); \
  __builtin_amdgcn_sched_barrier(0); \
  /* ---- P3: read b3 (k1, nf2-3); stage B(kt+2) j2,j3; MFMA a1xb3 ---- */ \
  _Pragma("unroll") \
  for (int nf=0; nf<2; ++nf) b3[nf] = *(const short8*)&Bb[bbase_r + (nf+2)*1024 + koff1]; \
  if (SB) { \
    const int kb_ = kt_ + 2; \
    const int tapb_ = kb_ >> 1; \
    const int dyb_ = tapb_/3; const int dxb_ = tapb_ - dyb_*3; \
    const int bdb_ = (dyb_*HP + dxb_)*CIN + (kb_&1)*64; \
    const int bb_ = (kb_ % 3) * 8192; \
    async_ld16(&Blds[bb_ + 4096 + bdst], &xpad[bsrc + 2*HP*CIN + bdb_]); \
    async_ld16(&Blds[bb_ + 6144 + bdst], &xpad[bsrc + 3*HP*CIN + bdb_]); \
  } \
  __builtin_amdgcn_s_barrier(); \
  asm volatile("s_waitcnt lgkmcnt(0)" ::: "memory"); \
  __builtin_amdgcn_sched_barrier(0); \
  __builtin_amdgcn_s_setprio(1); \
  _Pragma("unroll") \
  for (int mf=0; mf<4; ++mf) \
    _Pragma("unroll") \
    for (int nf=0; nf<2; ++nf) \
      acc[mf][nf+2] = __builtin_amdgcn_mfma_f32_16x16x32_bf16(a1[mf], b3[nf], acc[mf][nf+2], 0,0,0); \
  __builtin_amdgcn_s_setprio(0); \
}

__global__ __launch_bounds__(256, 2) void conv1(const ushort_t* __restrict__ xpad,
                                                const ushort_t* __restrict__ w1t,
                                                const float* __restrict__ b1,
                                                ushort_t* __restrict__ hpad){
  __shared__ __align__(16) ushort_t Alds[2*8192];   // 2 bufs x 128 rows x 64 (32 KB)
  __shared__ __align__(16) ushort_t Blds[3*8192];   // 3 bufs x 128 rows x 64 (48 KB)
  int orig = blockIdx.x;
  int bid = (orig & 7) * 288 + (orig >> 3);          // XCD swizzle, 2304 % 8 == 0
  int mt = bid & 1;
  int nt = bid >> 1;
  int b = nt / 72; int rem = nt - b*72;
  int y0 = (rem/3)*4, x0 = (rem - (rem/3)*3)*32;     // 4y x 32x pixel tile
  int o0 = mt*128;
  int t = threadIdx.x;
  int lane = t & 63, wave = t >> 6;
  int wm = wave & 1, wn = wave >> 1;                 // 2M x 2N waves (wave tile 64x64)
  int r = lane & 15, q = lane >> 4;

  // staging maps (granule u = j*256 + t; row = u>>3 = (t>>3)+32j; stored oct
  // u&7 holds logical oct (u&7)^(row&7) -> source pre-swizzled, dest linear)
  const int arow0 = t >> 3;                          // 0..31 (j adds 32 each)
  const int soct  = (t & 7) ^ (arow0 & 7);           // row&7 invariant in j
  const int adst  = t * 8;                           // + j*2048 + buf*8192
  const int asrc  = (o0 + arow0) * 1152 + soct * 8;  // + j*36864 + kt*64
  const int bdst  = t * 8;                           // + j*2048 + buf*8192
  const int bsrc  = ((b*HP + y0)*HP + x0 + arow0)*CIN + soct * 8;  // + j*HP*CIN + bd

  // fragment read offsets (ushort units); row&7 == r&7 for all frag rows
  const int koff0 = ((0*4 + q) ^ (r & 7)) * 8;
  const int koff1 = ((1*4 + q) ^ (r & 7)) * 8;
  const int abase_r = (wm*64 + r) * 64;              // + mf*1024 (mf 0..3)
  const int bbase_r = (wn*64 + r) * 64;              // + nf*1024 (nf 0..3)

  floatx4 acc[4][4];
  #pragma unroll
  for (int i=0;i<4;i++)
    #pragma unroll
    for (int j=0;j<4;j++) acc[i][j] = (floatx4){0.f,0.f,0.f,0.f};

  // prologue: ledger order B-for-0(4), A-for-0(4), B-for-1(4)
  #pragma unroll
  for (int j=0;j<4;++j) async_ld16(&Blds[0    + j*2048 + bdst], &xpad[bsrc + j*HP*CIN]);
  #pragma unroll
  for (int j=0;j<4;++j) async_ld16(&Alds[0    + j*2048 + adst], &w1t[asrc + j*36864]);
  #pragma unroll
  for (int j=0;j<4;++j) async_ld16(&Blds[8192 + j*2048 + bdst], &xpad[bsrc + j*HP*CIN + 64]);

  for (int kt=0; kt<16; ++kt){
    C1_TILE(kt, 4, 1, 1)
  }
  C1_TILE(16, 4, 1, 0)
  C1_TILE(17, 0, 0, 0)

  // epilogue: +bias, ReLU, bf16, store padded NHWC h
  #pragma unroll
  for (int mf=0; mf<4; ++mf){
    int o = o0 + wm*64 + mf*16 + q*4;
    float bias0 = b1[o], bias1 = b1[o+1], bias2 = b1[o+2], bias3 = b1[o+3];
    #pragma unroll
    for (int nf=0; nf<4; ++nf){
      int n = wn*64 + nf*16 + r;
      int ty = n >> 5, tx = n & 31;
      ushortx4 v;
      v[0] = f2bf(fmaxf(acc[mf][nf][0] + bias0, 0.f));
      v[1] = f2bf(fmaxf(acc[mf][nf][1] + bias1, 0.f));
      v[2] = f2bf(fmaxf(acc[mf][nf][2] + bias2, 0.f));
      v[3] = f2bf(fmaxf(acc[mf][nf][3] + bias3, 0.f));
      *(ushortx4*)&hpad[((b*HP + y0+ty+1)*HP + (x0+tx+1))*CH + o] = v;
    }
  }
}

// conv2: LDS-staged direct 3x3. Block = 8x8 output tile, halo 10x10 cells x 512B
// staged into LDS (51.2 KB) via global_load_lds: LDS dest linear, global SOURCE
// pre-swizzled chunk ^ (cell&7); reads apply the same XOR (both-sides involution).
// Wave = channel quarter (w addresses wave-uniform -> scalar cache); lane = pixel.
__global__ __launch_bounds__(256) void conv2(const ushort_t* __restrict__ hpad,
                                             const float* __restrict__ w2t,
                                             const float* __restrict__ b2,
                                             float* __restrict__ out){
  __shared__ __align__(16) ushort_t hlds[25600];   // 100 cells * 256 ushorts
  __shared__ float part[4][64][2];
  int bid = blockIdx.x;              // 2304 = 16 b * 12 yt * 12 xt
  int b = bid / 144; int rem = bid - b*144;
  int yt = rem / 12, xt = rem - yt*12;
  int y0 = yt*8, x0 = xt*8;          // padded window base = (y0, x0)
  int t = threadIdx.x;
  int wave = t >> 6, lane = t & 63;

  // stage 3200 x 16B chunks, pre-swizzled source
  for (int pass=0; pass<13; ++pass){
    int u = pass*256 + t;
    if (u < 3200){
      int cell = u >> 5, cf = u & 31;
      int hy = cell / 10, hx = cell - hy*10;
      const ushort_t* src = hpad + ((b*HP + y0+hy)*HP + (x0+hx))*CH
                                 + ((cf ^ (cell & 7)) << 3);
      async_ld16(&hlds[(pass*256 + wave*64)*8], src);
    }
  }
  __syncthreads();

  int q = __builtin_amdgcn_readfirstlane(wave);    // channel quarter, provably uniform
  int ty = lane >> 3, tx = lane & 7;
  float a0 = 0.f, a1 = 0.f;
  for (int tap=0; tap<9; ++tap){
    int dy = tap/3, dxx = tap - dy*3;
    int cell = (ty+dy)*10 + (tx+dxx);
    int s = cell & 7;
    const float* wp = w2t + (tap*256 + q*64)*2;    // scalar pointer
    #pragma unroll
    for (int g=0; g<8; ++g){
      int j = q*8 + g;
      ushortx8 hv = *(const ushortx8*)&hlds[cell*256 + ((j ^ s) << 3)];
      #pragma unroll
      for (int i=0;i<8;i++){
        float hf = bf2f(hv[i]);
        a0 = fmaf(hf, wp[(g*8+i)*2    ], a0);
        a1 = fmaf(hf, wp[(g*8+i)*2 + 1], a1);
      }
    }
  }
  part[wave][lane][0] = a0;
  part[wave][lane][1] = a1;
  __syncthreads();
  if (t < 128){
    int sel = t >> 6, pix = t & 63;
    float v = part[0][pix][sel] + part[1][pix][sel]
            + part[2][pix][sel] + part[3][pix][sel] + b2[sel];
    int yy = y0 + (pix >> 3), xx = x0 + (pix & 7);
    out[(b*2 + sel)*9216 + yy*96 + xx] = v;
  }
}

extern "C" void kernel_launch(void* const* d_in, const int* in_sizes, int n_in,
                              void* d_out, int out_size, void* d_ws, size_t ws_size,
                              hipStream_t stream){
  const float* x  = (const float*)d_in[0];
  const float* w1 = (const float*)d_in[1];
  const float* b1 = (const float*)d_in[2];
  const float* w2 = (const float*)d_in[3];
  const float* b2 = (const float*)d_in[4];
  float* out = (float*)d_out;
  char* ws = (char*)d_ws;
  ushort_t* xpad = (ushort_t*)(ws + XPAD_OFF);
  ushort_t* hpad = (ushort_t*)(ws + HPAD_OFF);
  ushort_t* w1t  = (ushort_t*)(ws + W1T_OFF);
  float*    w2t  = (float*)(ws + W2T_OFF);

  hipLaunchKernelGGL(prep_all, dim3(10434), dim3(256), 0, stream,
                     x, w1, w2, (uint32_t*)xpad, (uint32_t*)hpad, w1t, w2t, xpad);
  hipLaunchKernelGGL(conv1, dim3(2304), dim3(256), 0, stream, xpad, w1t, b1, hpad);
  hipLaunchKernelGGL(conv2, dim3(2304), dim3(256), 0, stream, hpad, w2t, b2, out);
}